// Round 16
// baseline (1719.932 us; speedup 1.0000x reference)
//
#include <hip/hip_runtime.h>
#include <math.h>

#define NS 100000
#define NB 50000
#define EE 1600000

#define BSH 8
#define BSZ 256                         // dst nodes per bucket
#define NBK_S ((NS + BSZ - 1) / BSZ)    // 391
#define NBK_B ((NB + BSZ - 1) / BSZ)    // 196
#define CHUNK 16384                     // hist chunking
#define NCH ((EE + CHUNK - 1) / CHUNK)  // 98
#define SCH 8192                        // sort chunking
#define NSC ((EE + SCH - 1) / SCH)      // 196

#define SRC_MASK 0x1FFFF
#define SSH 17

#define GS_BLKS (NS / 32)               // 3125 (NS % 32 == 0)
#define GB_BLKS ((NB + 31) / 32)        // 1563

typedef unsigned int u32;
typedef unsigned short u16;

// ---------------- k1: per-chunk bucket histogram ----------------

__global__ __launch_bounds__(256) void hist_kernel(
    const int* __restrict__ e0, const int* __restrict__ e1, const int* __restrict__ e2,
    const int* __restrict__ e3, const int* __restrict__ e4, int* __restrict__ bcnt)
{
    int j = blockIdx.x, rel = blockIdx.y, tid = threadIdx.x;
    const int* ei = (rel == 0) ? e0 : (rel == 1) ? e1 : (rel == 2) ? e2 : (rel == 3) ? e3 : e4;
    int nb = (rel == 2 || rel == 3) ? NBK_B : NBK_S;
    __shared__ int hist[NBK_S];
    for (int i = tid; i < nb; i += 256) hist[i] = 0;
    __syncthreads();
    int es = j * CHUNK, ee2 = min(EE, es + CHUNK);
    for (int e = es + tid; e < ee2; e += 256)
        atomicAdd(&hist[ei[EE + e] >> BSH], 1);
    __syncthreads();
    for (int i = tid; i < nb; i += 256)
        if (hist[i]) atomicAdd(&bcnt[rel * NBK_S + i], hist[i]);
}

// ---------------- k2: per-relation bucket-base scan (+ cursor init) ----------------

__global__ __launch_bounds__(512) void bscan_kernel(const int* __restrict__ bcnt,
                                                    int* __restrict__ bbase,
                                                    int* __restrict__ gcur)
{
    int rel = blockIdx.x;
    int nb = (rel == 2 || rel == 3) ? NBK_B : NBK_S;
    __shared__ int s[512];
    int tid = threadIdx.x;
    int v = (tid < nb) ? bcnt[rel * NBK_S + tid] : 0;
    s[tid] = v;
    __syncthreads();
    for (int off = 1; off < 512; off <<= 1) {
        int t = (tid >= off) ? s[tid - off] : 0;
        __syncthreads();
        s[tid] += t;
        __syncthreads();
    }
    int ex = s[tid] - v;
    if (tid < nb) { bbase[rel * NBK_S + tid] = ex; gcur[rel * NBK_S + tid] = ex; }
}

// ---------------- k3: per-chunk LDS counting sort -> bucket-partitioned runs -------

__global__ __launch_bounds__(256, 4) void sort_kernel(
    const int* __restrict__ e0, const int* __restrict__ e1, const int* __restrict__ e2,
    const int* __restrict__ e3, const int* __restrict__ e4,
    int* __restrict__ ebkt, int* __restrict__ gcur)
{
    int j = blockIdx.x, rel = blockIdx.y, tid = threadIdx.x;
    const int* ei = (rel == 0) ? e0 : (rel == 1) ? e1 : (rel == 2) ? e2 : (rel == 3) ? e3 : e4;
    int nb = (rel == 2 || rel == 3) ? NBK_B : NBK_S;

    __shared__ int start[NBK_S + 1];
    __shared__ int cur[NBK_S];
    __shared__ int gbase[NBK_S];
    __shared__ int part[256];
    __shared__ int buf[SCH];

    int es = j * SCH, ee2 = min(EE, es + SCH);
    int n = ee2 - es;

    for (int i = tid; i < nb; i += 256) cur[i] = 0;     // cur = hist (temp)
    __syncthreads();
    for (int e = es + tid; e < ee2; e += 256)
        atomicAdd(&cur[ei[EE + e] >> BSH], 1);
    __syncthreads();

    int v0 = (2 * tid < nb) ? cur[2 * tid] : 0;
    int v1 = (2 * tid + 1 < nb) ? cur[2 * tid + 1] : 0;
    part[tid] = v0 + v1;
    __syncthreads();
    for (int off = 1; off < 256; off <<= 1) {
        int t = (tid >= off) ? part[tid - off] : 0;
        __syncthreads();
        part[tid] += t;
        __syncthreads();
    }
    int run = (tid > 0) ? part[tid - 1] : 0;
    if (2 * tid < nb) start[2 * tid] = run;
    if (2 * tid + 1 < nb) start[2 * tid + 1] = run + v0;
    if (tid == 0) start[nb] = n;
    __syncthreads();
    for (int i = tid; i < nb; i += 256) cur[i] = start[i];  // cursors
    __syncthreads();

    for (int e = es + tid; e < ee2; e += 256) {
        int s = ei[e], d = ei[EE + e];
        int pos = atomicAdd(&cur[d >> BSH], 1);
        buf[pos] = ((d & (BSZ - 1)) << SSH) | s;
    }
    for (int b = tid; b < nb; b += 256) {
        int c = start[b + 1] - start[b];
        gbase[b] = c ? atomicAdd(&gcur[rel * NBK_S + b], c) : 0;
    }
    __syncthreads();

    // stream out: 16-lane groups copy bucket runs (avg run ~21)
    int* eo = ebkt + (size_t)rel * EE;
    int w16 = tid >> 4, l16 = tid & 15;
    for (int b = w16; b < nb; b += 16) {
        int sb = start[b], c = start[b + 1] - sb, gb = gbase[b];
        for (int i = l16; i < c; i += 16)
            eo[gb + i] = buf[sb + i];
    }
}

// ---------------- k4: per-bucket CSR finalize ----------------

__global__ __launch_bounds__(256, 8) void csr_kernel(
    const int* __restrict__ ebkt, const int* __restrict__ bcnt, const int* __restrict__ bbase,
    int* __restrict__ edges_csr, int* __restrict__ rs_all)
{
    int bkt = blockIdx.x, rel = blockIdx.y, tid = threadIdx.x;
    int nb = (rel == 2 || rel == 3) ? NBK_B : NBK_S;
    if (bkt >= nb) return;
    int nd = (rel == 2 || rel == 3) ? NB : NS;

    int base = bbase[rel * NBK_S + bkt];
    int cnt = bcnt[rel * NBK_S + bkt];
    const int* span = ebkt + (size_t)rel * EE + base;
    int* rs = rs_all + rel * (NS + 1);

    __shared__ int h[BSZ], s[BSZ], cu[BSZ];
    h[tid] = 0;
    __syncthreads();
    for (int i = tid; i < cnt; i += 256)
        atomicAdd(&h[span[i] >> SSH], 1);
    __syncthreads();
    s[tid] = h[tid];
    __syncthreads();
    for (int off = 1; off < 256; off <<= 1) {
        int t = (tid >= off) ? s[tid - off] : 0;
        __syncthreads();
        s[tid] += t;
        __syncthreads();
    }
    int exv = s[tid] - h[tid];
    cu[tid] = exv;
    int node = bkt * BSZ + tid;
    if (node < nd) rs[node] = base + exv;
    if (bkt == nb - 1 && tid == 0) rs[nd] = base + cnt;
    __syncthreads();

    int* outp = edges_csr + (size_t)rel * EE;
    for (int i = tid; i < cnt; i += 256) {
        int p = span[i];
        int pos = atomicAdd(&cu[p >> SSH], 1);
        outp[base + pos] = p & SRC_MASK;
    }
}

// ---------------- bf16 helpers ----------------

__device__ __forceinline__ u32 bfpack(float a, float b) {
    u32 ua = __float_as_uint(a), ub = __float_as_uint(b);
    ua = (ua + 0x7fffu + ((ua >> 16) & 1u)) >> 16;
    ub = (ub + 0x7fffu + ((ub >> 16) & 1u)) >> 16;
    return ua | (ub << 16);
}
__device__ __forceinline__ u16 bf1(float f) {
    u32 u = __float_as_uint(f);
    return (u16)((u + 0x7fffu + ((u >> 16) & 1u)) >> 16);
}
__device__ __forceinline__ float bflo(u32 u) { return __uint_as_float(u << 16); }
__device__ __forceinline__ float bfhi(u32 u) { return __uint_as_float(u & 0xffff0000u); }

// ---------------- k5: pack D=6 f32 rows -> bf16[*][8] (one uint4/row) ----------------

__global__ __launch_bounds__(256) void pack6_kernel(
    const float* __restrict__ xs, const float* __restrict__ xb,
    u32* __restrict__ xps, u32* __restrict__ xpb)
{
    int i = blockIdx.x * 256 + threadIdx.x;
    const int totS = NS * 4, tot = (NS + NB) * 4;
    if (i >= tot) return;
    const float* src; u32* dst; int j;
    if (i < totS) { src = xs; dst = xps; j = i; }
    else          { src = xb; dst = xpb; j = i - totS; }
    int node = j >> 2, w = j & 3;
    int d0 = 2 * w, d1 = 2 * w + 1;
    float a = (d0 < 6) ? src[(size_t)node * 6 + d0] : 0.f;
    float b = (d1 < 6) ? src[(size_t)node * 6 + d1] : 0.f;
    dst[j] = bfpack(a, b);
}

// ---------------- FRel ----------------

struct FRel {
    const int* rs;
    const int* srcs;
    const void* xsrc;
    const float* W;
    const float* b;
    const float* Wroot;
};

// ================= D=32 path: R13-proven body (16-edge rounds, unpack+fmaf) =======

template <int AGGR>
__device__ __forceinline__ void gath32bf(const u32* __restrict__ xsrc,
                                         const int* __restrict__ srcs,
                                         int s0, int deg, int li, int l8,
                                         float (&acc)[8])
{
    float init = (AGGR == 2) ? -INFINITY : 0.f;
    #pragma unroll
    for (int d = 0; d < 8; ++d) acc[d] = init;
    int grp = l8 >> 2, q = l8 & 3;
    int lim = s0 + deg - 1;
    int obase = li & ~7;
    for (int bs = 0; bs < deg; bs += 16) {
        int a0 = s0 + bs + 2 * l8;
        int ix0 = srcs[a0 < lim ? a0 : lim];
        int ix1 = srcs[a0 + 1 < lim ? a0 + 1 : lim];
        #pragma unroll
        for (int sub = 0; sub < 8; ++sub) {
            int sa = __shfl(ix0, obase + sub, 64);
            int sb = __shfl(ix1, obase + sub, 64);
            int s = grp ? sb : sa;
            int e = bs + 2 * sub + grp;
            if (e < deg) {
                uint4 v = *reinterpret_cast<const uint4*>(xsrc + (size_t)s * 16 + q * 4);
                float f0 = bflo(v.x), f1 = bfhi(v.x), f2 = bflo(v.y), f3 = bfhi(v.y);
                float f4 = bflo(v.z), f5 = bfhi(v.z), f6 = bflo(v.w), f7 = bfhi(v.w);
                if (AGGR == 2) {
                    acc[0] = fmaxf(acc[0], f0); acc[1] = fmaxf(acc[1], f1);
                    acc[2] = fmaxf(acc[2], f2); acc[3] = fmaxf(acc[3], f3);
                    acc[4] = fmaxf(acc[4], f4); acc[5] = fmaxf(acc[5], f5);
                    acc[6] = fmaxf(acc[6], f6); acc[7] = fmaxf(acc[7], f7);
                } else {
                    acc[0] += f0; acc[1] += f1; acc[2] += f2; acc[3] += f3;
                    acc[4] += f4; acc[5] += f5; acc[6] += f6; acc[7] += f7;
                }
            }
        }
    }
    #pragma unroll
    for (int d = 0; d < 8; ++d) {
        float o = __shfl_xor(acc[d], 4, 64);
        acc[d] = (AGGR == 2) ? fmaxf(acc[d], o) : (acc[d] + o);
    }
}

template <int AGGR>
__device__ __forceinline__ void do_g32(const FRel& R, int node, int nd,
                                       int li, int l8, int nl, u32* aggP)
{
    int nodec = min(node, nd - 1);
    int s0 = R.rs[nodec];
    int deg = R.rs[nodec + 1] - s0;
    if (node >= nd) deg = 0;
    float acc[8];
    gath32bf<AGGR>((const u32*)R.xsrc, R.srcs, s0, deg, li, l8, acc);
    if (AGGR == 1) {
        float inv = 1.f / (float)max(deg, 1);
        #pragma unroll
        for (int d = 0; d < 8; ++d) acc[d] *= inv;
    }
    if (AGGR == 2 && deg == 0) {
        #pragma unroll
        for (int d = 0; d < 8; ++d) acc[d] = 0.f;
    }
    int grp = l8 >> 2, q = l8 & 3;
    uint2 o;
    if (grp == 0) { o.x = bfpack(acc[0], acc[1]); o.y = bfpack(acc[2], acc[3]); }
    else          { o.x = bfpack(acc[4], acc[5]); o.y = bfpack(acc[6], acc[7]); }
    *reinterpret_cast<uint2*>(aggP + nl * 16 + q * 4 + grp * 2) = o;
}

// R13 kernel body, factored: LDS passed as fixed-size array refs (static addressing
// preserved after inlining). node_base replaces blockIdx.x*32.
template <int NREL, bool RES, bool RELU, bool OUTBF, int A0, int A1, int A2>
__device__ __forceinline__ void fused32_body(
    const FRel& r0, const FRel& r1, const FRel& r2,
    const void* xdst, void* outp, int nd, int node_base,
    u32 (&sWb)[3 * 512], float (&sWr)[32 * 32], u32 (&aggP)[3 * 512], u32 (&xP)[512])
{
    int tid = threadIdx.x, li = tid & 63, l8 = tid & 7, nl = tid >> 3;
    int node = node_base + nl;
    bool valid = node < nd;

    for (int i = tid; i < 16 * 32; i += 256) {
        int k2 = i >> 5, dim = i & 31;
        sWb[0 * 512 + i] = bfpack(r0.W[(2 * k2) * 32 + dim], r0.W[(2 * k2 + 1) * 32 + dim]);
        if (NREL > 1) sWb[1 * 512 + i] = bfpack(r1.W[(2 * k2) * 32 + dim], r1.W[(2 * k2 + 1) * 32 + dim]);
        if (NREL > 2) sWb[2 * 512 + i] = bfpack(r2.W[(2 * k2) * 32 + dim], r2.W[(2 * k2 + 1) * 32 + dim]);
    }
    for (int i = tid; i < 32 * 32; i += 256) {
        float wv = r0.Wroot[i];
        if (NREL > 1) wv += r1.Wroot[i];
        if (NREL > 2) wv += r2.Wroot[i];
        sWr[i] = wv;
    }

    uint2 xv = {0u, 0u};
    if (valid) xv = *reinterpret_cast<const uint2*>((const u32*)xdst + (size_t)node * 16 + l8 * 2);
    xP[nl * 16 + l8 * 2] = xv.x;
    xP[nl * 16 + l8 * 2 + 1] = xv.y;

    do_g32<A0>(r0, node, nd, li, l8, nl, aggP + 0 * 512);
    if (NREL > 1) do_g32<A1>(r1, node, nd, li, l8, nl, aggP + 1 * 512);
    if (NREL > 2) do_g32<A2>(r2, node, nd, li, l8, nl, aggP + 2 * 512);

    __syncthreads();

    int dim = tid & 31, grp = tid >> 5;
    #pragma unroll
    for (int it = 0; it < 4; ++it) {
        int n2 = grp + it * 8;
        int gnode = node_base + n2;
        if (gnode < nd) {
            float mm = r0.b[dim];
            if (NREL > 1) mm += r1.b[dim];
            if (NREL > 2) mm += r2.b[dim];
            #pragma unroll
            for (int r = 0; r < NREL; ++r) {
                const u32* ar = aggP + r * 512 + n2 * 16;
                const u32* wr = sWb + r * 512;
                #pragma unroll
                for (int k2 = 0; k2 < 16; ++k2) {
                    u32 a = ar[k2];
                    u32 w = wr[k2 * 32 + dim];
                    mm = fmaf(bflo(a), bflo(w), mm);
                    mm = fmaf(bfhi(a), bfhi(w), mm);
                }
            }
            const u32* xr = xP + n2 * 16;
            #pragma unroll
            for (int k2 = 0; k2 < 16; ++k2) {
                u32 u = xr[k2];
                mm = fmaf(bflo(u), sWr[(2 * k2) * 32 + dim], mm);
                mm = fmaf(bfhi(u), sWr[(2 * k2 + 1) * 32 + dim], mm);
            }
            if (RES) {
                u32 u = xr[dim >> 1];
                mm += (dim & 1) ? bfhi(u) : bflo(u);
            }
            if (RELU) mm = fmaxf(mm, 0.f);
            if (OUTBF) ((u16*)outp)[(size_t)gnode * 32 + dim] = bf1(mm);
            else       ((float*)outp)[(size_t)gnode * 32 + dim] = mm;
        }
    }
}

// Dual-grid layer kernel: blocks [0,GS) = stroke (NREL=3), [GS,GS+GB) = brep (NREL=2).
// Packs brep blocks into the stroke launch tail (independent work, disjoint outputs).
template <bool RES, bool RELU, bool OUTBF>
__global__ __launch_bounds__(256, 8) void fused32_dual_kernel(
    FRel s0, FRel s1, FRel s2, FRel b0, FRel b1,
    const void* xs, const void* xb, void* outs, void* outb)
{
    __shared__ u32 sWb[3 * 512];
    __shared__ float sWr[32 * 32];
    __shared__ u32 aggP[3 * 512];
    __shared__ u32 xP[512];

    int bid = blockIdx.x;
    if (bid < GS_BLKS) {
        fused32_body<3, RES, RELU, OUTBF, 1, 0, 2>(
            s0, s1, s2, xs, outs, NS, bid * 32, sWb, sWr, aggP, xP);
    } else {
        fused32_body<2, RES, RELU, OUTBF, 1, 2, 0>(
            b0, b1, b0, xb, outb, NB, (bid - GS_BLKS) * 32, sWb, sWr, aggP, xP);
    }
}

// ================= D=6 layer-0 path (separate template; proven) =======

template <int AGGR>
__device__ __forceinline__ void gath6p(const u32* __restrict__ xsrc,
                                       const int* __restrict__ srcs,
                                       int s0, int deg, int l8, float (&acc)[6])
{
    float init = (AGGR == 2) ? -INFINITY : 0.f;
    #pragma unroll
    for (int d = 0; d < 6; ++d) acc[d] = init;
    for (int bs = 0; bs < deg; bs += 8) {
        int e = bs + l8;
        int a = s0 + (e < deg ? e : deg - 1);
        int idx = srcs[a];
        if (e < deg) {
            uint4 v = *reinterpret_cast<const uint4*>(xsrc + (size_t)idx * 4);
            float f0 = bflo(v.x), f1 = bfhi(v.x), f2 = bflo(v.y);
            float f3 = bfhi(v.y), f4 = bflo(v.z), f5 = bfhi(v.z);
            if (AGGR == 2) {
                acc[0] = fmaxf(acc[0], f0); acc[1] = fmaxf(acc[1], f1);
                acc[2] = fmaxf(acc[2], f2); acc[3] = fmaxf(acc[3], f3);
                acc[4] = fmaxf(acc[4], f4); acc[5] = fmaxf(acc[5], f5);
            } else {
                acc[0] += f0; acc[1] += f1; acc[2] += f2;
                acc[3] += f3; acc[4] += f4; acc[5] += f5;
            }
        }
    }
    #pragma unroll
    for (int m = 1; m <= 4; m <<= 1) {
        #pragma unroll
        for (int d = 0; d < 6; ++d) {
            float o = __shfl_xor(acc[d], m, 64);   // intra-octet, full-wave
            acc[d] = (AGGR == 2) ? fmaxf(acc[d], o) : (acc[d] + o);
        }
    }
}

template <int AGGR>
__device__ __forceinline__ void do_g6(const FRel& R, int node, int nd,
                                      int l8, int nl, float* aggF)
{
    int nodec = min(node, nd - 1);
    int s0 = R.rs[nodec];
    int deg = R.rs[nodec + 1] - s0;
    if (node >= nd) deg = 0;
    float acc[6];
    gath6p<AGGR>((const u32*)R.xsrc, R.srcs, s0, deg, l8, acc);
    if (AGGR == 1) {
        float inv = 1.f / (float)max(deg, 1);
        #pragma unroll
        for (int d = 0; d < 6; ++d) acc[d] *= inv;
    }
    if (AGGR == 2 && deg == 0) {
        #pragma unroll
        for (int d = 0; d < 6; ++d) acc[d] = 0.f;
    }
    if (l8 == 0) {
        #pragma unroll
        for (int d = 0; d < 6; ++d) aggF[nl * 8 + d] = acc[d];
        aggF[nl * 8 + 6] = 0.f; aggF[nl * 8 + 7] = 0.f;
    }
}

template <int NREL, int A0, int A1, int A2>
__global__ __launch_bounds__(256, 8) void fused6_kernel(
    FRel r0, FRel r1, FRel r2,
    const float* __restrict__ xdst, u16* __restrict__ outp, int nd)
{
    __shared__ float sW6[NREL * 6 * 32];
    __shared__ float sWr[6 * 32];
    __shared__ float aggF[NREL * 32 * 8];
    __shared__ float xF[32 * 8];

    int tid = threadIdx.x, l8 = tid & 7, nl = tid >> 3;
    int node = blockIdx.x * 32 + nl;
    bool valid = node < nd;

    for (int i = tid; i < 6 * 32; i += 256) {
        sW6[0 * 192 + i] = r0.W[i];
        if (NREL > 1) sW6[1 * 192 + i] = r1.W[i];
        if (NREL > 2) sW6[2 * 192 + i] = r2.W[i];
        float wv = r0.Wroot[i];
        if (NREL > 1) wv += r1.Wroot[i];
        if (NREL > 2) wv += r2.Wroot[i];
        sWr[i] = wv;
    }
    xF[nl * 8 + l8] = (valid && l8 < 6) ? xdst[(size_t)node * 6 + l8] : 0.f;

    do_g6<A0>(r0, node, nd, l8, nl, aggF + 0 * 256);
    if (NREL > 1) do_g6<A1>(r1, node, nd, l8, nl, aggF + 1 * 256);
    if (NREL > 2) do_g6<A2>(r2, node, nd, l8, nl, aggF + 2 * 256);

    __syncthreads();

    int dim = tid & 31, grp = tid >> 5;
    #pragma unroll
    for (int it = 0; it < 4; ++it) {
        int n2 = grp + it * 8;
        int gnode = blockIdx.x * 32 + n2;
        if (gnode < nd) {
            float mm = r0.b[dim];
            if (NREL > 1) mm += r1.b[dim];
            if (NREL > 2) mm += r2.b[dim];
            #pragma unroll
            for (int r = 0; r < NREL; ++r)
                #pragma unroll
                for (int k = 0; k < 6; ++k)
                    mm = fmaf(aggF[r * 256 + n2 * 8 + k], sW6[r * 192 + k * 32 + dim], mm);
            #pragma unroll
            for (int k = 0; k < 6; ++k)
                mm = fmaf(xF[n2 * 8 + k], sWr[k * 32 + dim], mm);
            outp[(size_t)gnode * 32 + dim] = bf1(mm);
        }
    }
}

// ---------------- host ----------------

static inline char* alignp(char* p, size_t a) {
    return (char*)(((uintptr_t)p + a - 1) & ~(a - 1));
}

extern "C" void kernel_launch(void* const* d_in, const int* in_sizes, int n_in,
                              void* d_out, int out_size, void* d_ws, size_t ws_size,
                              hipStream_t stream)
{
    const float* x_stroke = (const float*)d_in[0];
    const float* x_brep   = (const float*)d_in[1];
    const int* ei0 = (const int*)d_in[2];
    const int* ei1 = (const int*)d_in[3];
    const int* ei2 = (const int*)d_in[4];
    const int* ei3 = (const int*)d_in[5];
    const int* ei4 = (const int*)d_in[6];
    const float* W0_rel  = (const float*)d_in[7];
    const float* b0_rel  = (const float*)d_in[8];
    const float* W0_root = (const float*)d_in[9];
    const float* Wb_rel  = (const float*)d_in[10];
    const float* bb_rel  = (const float*)d_in[11];
    const float* Wb_root = (const float*)d_in[12];
    float* out = (float*)d_out;

    // ---- workspace ----
    char* A = alignp((char*)d_ws, 256);
    int* ebkt = (int*)A;                                 // 5*EE ints (dead after csr_kernel)
    u32* xs0 = (u32*)A;                                  // overlay after build
    u32* xb0 = xs0 + (size_t)NS * 16;
    u32* xps = xb0 + (size_t)NB * 16;                    // packed D=6 rows (overlay)
    u32* xpb = xps + (size_t)NS * 4;
    char* Aend = (char*)(ebkt + (size_t)5 * EE);
    u32* xs1 = (u32*)alignp(Aend, 256);
    u32* xb1 = xs1 + (size_t)NS * 16;
    int* edges_csr = (int*)alignp((char*)(xb1 + (size_t)NB * 16), 256);   // 5*EE
    int* rs_all = (int*)alignp((char*)(edges_csr + (size_t)5 * EE), 256); // 5*(NS+1)
    int* bcnt  = (int*)alignp((char*)(rs_all + 5 * (NS + 1)), 256);
    int* bbase = (int*)alignp((char*)(bcnt + 5 * NBK_S), 256);
    int* gcur  = (int*)alignp((char*)(bbase + 5 * NBK_S), 256);

    // ---- build ----
    hipMemsetAsync(bcnt, 0, 5 * NBK_S * sizeof(int), stream);
    hist_kernel<<<dim3(NCH, 5), 256, 0, stream>>>(ei0, ei1, ei2, ei3, ei4, bcnt);
    bscan_kernel<<<5, 512, 0, stream>>>(bcnt, bbase, gcur);
    sort_kernel<<<dim3(NSC, 5), 256, 0, stream>>>(ei0, ei1, ei2, ei3, ei4, ebkt, gcur);
    csr_kernel<<<dim3(NBK_S, 5), 256, 0, stream>>>(ebkt, bcnt, bbase, edges_csr, rs_all);
    pack6_kernel<<<((NS + NB) * 4 + 255) / 256, 256, 0, stream>>>(x_stroke, x_brep, xps, xpb);

    // ---- weights ----
    auto relW = [&](int l, int r) -> const float* {
        return l == 0 ? W0_rel + r * 6 * 32 : Wb_rel + ((l - 1) * 5 + r) * 32 * 32;
    };
    auto relB = [&](int l, int r) -> const float* {
        return l == 0 ? b0_rel + r * 32 : bb_rel + ((l - 1) * 5 + r) * 32;
    };
    auto relWr = [&](int l, int r) -> const float* {
        return l == 0 ? W0_root + r * 6 * 32 : Wb_root + ((l - 1) * 5 + r) * 32 * 32;
    };
    auto FR = [&](int l, int r, const void* xsrc) -> FRel {
        FRel R;
        R.rs = rs_all + r * (NS + 1);
        R.srcs = edges_csr + (size_t)r * EE;
        R.xsrc = xsrc;
        R.W = relW(l, r); R.b = relB(l, r); R.Wroot = relWr(l, r);
        return R;
    };

    const int GS = GS_BLKS;   // 3125
    const int GB = GB_BLKS;   // 1563

    // layer 0 (D=6, packed bf16 sources; f32 root; no residual) -> bf16 xs0/xb0
    fused6_kernel<3, 1, 0, 2><<<GS, 256, 0, stream>>>(
        FR(0, 0, xps), FR(0, 1, xps), FR(0, 4, xps), x_stroke, (u16*)xs0, NS);
    fused6_kernel<2, 1, 2, 0><<<GB, 256, 0, stream>>>(
        FR(0, 2, xps), FR(0, 3, xpb), FR(0, 2, xps), x_brep, (u16*)xb0, NB);

    // layers 1..3 (D=32 bf16, residual, ping-pong, dual-grid); layer 4 relu -> f32 d_out
    const u32* cs = xs0; const u32* cb = xb0;
    for (int l = 1; l <= 3; ++l) {
        u32* os = (l & 1) ? xs1 : xs0;
        u32* ob = (l & 1) ? xb1 : xb0;
        fused32_dual_kernel<true, false, true><<<GS + GB, 256, 0, stream>>>(
            FR(l, 0, cs), FR(l, 1, cs), FR(l, 4, cs), FR(l, 2, cs), FR(l, 3, cb),
            cs, cb, os, ob);
        cs = os; cb = ob;
    }
    fused32_dual_kernel<true, true, false><<<GS + GB, 256, 0, stream>>>(
        FR(4, 0, cs), FR(4, 1, cs), FR(4, 4, cs), FR(4, 2, cs), FR(4, 3, cb),
        cs, cb, out, out + (size_t)NS * 32);

    (void)in_sizes; (void)n_in; (void)out_size; (void)ws_size;
}

// Round 17
// 684.866 us; speedup vs baseline: 2.5113x; 2.5113x over previous
//
#include <hip/hip_runtime.h>
#include <math.h>

#define NS 100000
#define NB 50000
#define EE 1600000

#define BSH 8
#define BSZ 256                         // dst nodes per bucket
#define NBK_S ((NS + BSZ - 1) / BSZ)    // 391
#define NBK_B ((NB + BSZ - 1) / BSZ)    // 196
#define CHUNK 16384                     // hist chunking
#define NCH ((EE + CHUNK - 1) / CHUNK)  // 98
#define SCH 8192                        // sort chunking
#define NSC ((EE + SCH - 1) / SCH)      // 196

#define SRC_MASK 0x1FFFF
#define SSH 17

typedef unsigned int u32;
typedef unsigned short u16;

// ---------------- k1: per-chunk bucket histogram ----------------

__global__ __launch_bounds__(256) void hist_kernel(
    const int* __restrict__ e0, const int* __restrict__ e1, const int* __restrict__ e2,
    const int* __restrict__ e3, const int* __restrict__ e4, int* __restrict__ bcnt)
{
    int j = blockIdx.x, rel = blockIdx.y, tid = threadIdx.x;
    const int* ei = (rel == 0) ? e0 : (rel == 1) ? e1 : (rel == 2) ? e2 : (rel == 3) ? e3 : e4;
    int nb = (rel == 2 || rel == 3) ? NBK_B : NBK_S;
    __shared__ int hist[NBK_S];
    for (int i = tid; i < nb; i += 256) hist[i] = 0;
    __syncthreads();
    int es = j * CHUNK, ee2 = min(EE, es + CHUNK);
    for (int e = es + tid; e < ee2; e += 256)
        atomicAdd(&hist[ei[EE + e] >> BSH], 1);
    __syncthreads();
    for (int i = tid; i < nb; i += 256)
        if (hist[i]) atomicAdd(&bcnt[rel * NBK_S + i], hist[i]);
}

// ---------------- k2: per-relation bucket-base scan (+ cursor init) ----------------

__global__ __launch_bounds__(512) void bscan_kernel(const int* __restrict__ bcnt,
                                                    int* __restrict__ bbase,
                                                    int* __restrict__ gcur)
{
    int rel = blockIdx.x;
    int nb = (rel == 2 || rel == 3) ? NBK_B : NBK_S;
    __shared__ int s[512];
    int tid = threadIdx.x;
    int v = (tid < nb) ? bcnt[rel * NBK_S + tid] : 0;
    s[tid] = v;
    __syncthreads();
    for (int off = 1; off < 512; off <<= 1) {
        int t = (tid >= off) ? s[tid - off] : 0;
        __syncthreads();
        s[tid] += t;
        __syncthreads();
    }
    int ex = s[tid] - v;
    if (tid < nb) { bbase[rel * NBK_S + tid] = ex; gcur[rel * NBK_S + tid] = ex; }
}

// ---------------- k3: per-chunk LDS counting sort -> bucket-partitioned runs -------

__global__ __launch_bounds__(256, 4) void sort_kernel(
    const int* __restrict__ e0, const int* __restrict__ e1, const int* __restrict__ e2,
    const int* __restrict__ e3, const int* __restrict__ e4,
    int* __restrict__ ebkt, int* __restrict__ gcur)
{
    int j = blockIdx.x, rel = blockIdx.y, tid = threadIdx.x;
    const int* ei = (rel == 0) ? e0 : (rel == 1) ? e1 : (rel == 2) ? e2 : (rel == 3) ? e3 : e4;
    int nb = (rel == 2 || rel == 3) ? NBK_B : NBK_S;

    __shared__ int start[NBK_S + 1];
    __shared__ int cur[NBK_S];
    __shared__ int gbase[NBK_S];
    __shared__ int part[256];
    __shared__ int buf[SCH];

    int es = j * SCH, ee2 = min(EE, es + SCH);
    int n = ee2 - es;

    for (int i = tid; i < nb; i += 256) cur[i] = 0;     // cur = hist (temp)
    __syncthreads();
    for (int e = es + tid; e < ee2; e += 256)
        atomicAdd(&cur[ei[EE + e] >> BSH], 1);
    __syncthreads();

    int v0 = (2 * tid < nb) ? cur[2 * tid] : 0;
    int v1 = (2 * tid + 1 < nb) ? cur[2 * tid + 1] : 0;
    part[tid] = v0 + v1;
    __syncthreads();
    for (int off = 1; off < 256; off <<= 1) {
        int t = (tid >= off) ? part[tid - off] : 0;
        __syncthreads();
        part[tid] += t;
        __syncthreads();
    }
    int run = (tid > 0) ? part[tid - 1] : 0;
    if (2 * tid < nb) start[2 * tid] = run;
    if (2 * tid + 1 < nb) start[2 * tid + 1] = run + v0;
    if (tid == 0) start[nb] = n;
    __syncthreads();
    for (int i = tid; i < nb; i += 256) cur[i] = start[i];  // cursors
    __syncthreads();

    for (int e = es + tid; e < ee2; e += 256) {
        int s = ei[e], d = ei[EE + e];
        int pos = atomicAdd(&cur[d >> BSH], 1);
        buf[pos] = ((d & (BSZ - 1)) << SSH) | s;
    }
    for (int b = tid; b < nb; b += 256) {
        int c = start[b + 1] - start[b];
        gbase[b] = c ? atomicAdd(&gcur[rel * NBK_S + b], c) : 0;
    }
    __syncthreads();

    // stream out: 16-lane groups copy bucket runs (avg run ~21)
    int* eo = ebkt + (size_t)rel * EE;
    int w16 = tid >> 4, l16 = tid & 15;
    for (int b = w16; b < nb; b += 16) {
        int sb = start[b], c = start[b + 1] - sb, gb = gbase[b];
        for (int i = l16; i < c; i += 16)
            eo[gb + i] = buf[sb + i];
    }
}

// ---------------- k4: per-bucket CSR finalize ----------------

__global__ __launch_bounds__(256, 8) void csr_kernel(
    const int* __restrict__ ebkt, const int* __restrict__ bcnt, const int* __restrict__ bbase,
    int* __restrict__ edges_csr, int* __restrict__ rs_all)
{
    int bkt = blockIdx.x, rel = blockIdx.y, tid = threadIdx.x;
    int nb = (rel == 2 || rel == 3) ? NBK_B : NBK_S;
    if (bkt >= nb) return;
    int nd = (rel == 2 || rel == 3) ? NB : NS;

    int base = bbase[rel * NBK_S + bkt];
    int cnt = bcnt[rel * NBK_S + bkt];
    const int* span = ebkt + (size_t)rel * EE + base;
    int* rs = rs_all + rel * (NS + 1);

    __shared__ int h[BSZ], s[BSZ], cu[BSZ];
    h[tid] = 0;
    __syncthreads();
    for (int i = tid; i < cnt; i += 256)
        atomicAdd(&h[span[i] >> SSH], 1);
    __syncthreads();
    s[tid] = h[tid];
    __syncthreads();
    for (int off = 1; off < 256; off <<= 1) {
        int t = (tid >= off) ? s[tid - off] : 0;
        __syncthreads();
        s[tid] += t;
        __syncthreads();
    }
    int exv = s[tid] - h[tid];
    cu[tid] = exv;
    int node = bkt * BSZ + tid;
    if (node < nd) rs[node] = base + exv;
    if (bkt == nb - 1 && tid == 0) rs[nd] = base + cnt;
    __syncthreads();

    int* outp = edges_csr + (size_t)rel * EE;
    for (int i = tid; i < cnt; i += 256) {
        int p = span[i];
        int pos = atomicAdd(&cu[p >> SSH], 1);
        outp[base + pos] = p & SRC_MASK;
    }
}

// ---------------- bf16 helpers ----------------

__device__ __forceinline__ u32 bfpack(float a, float b) {
    u32 ua = __float_as_uint(a), ub = __float_as_uint(b);
    ua = (ua + 0x7fffu + ((ua >> 16) & 1u)) >> 16;
    ub = (ub + 0x7fffu + ((ub >> 16) & 1u)) >> 16;
    return ua | (ub << 16);
}
__device__ __forceinline__ u16 bf1(float f) {
    u32 u = __float_as_uint(f);
    return (u16)((u + 0x7fffu + ((u >> 16) & 1u)) >> 16);
}
__device__ __forceinline__ float bflo(u32 u) { return __uint_as_float(u << 16); }
__device__ __forceinline__ float bfhi(u32 u) { return __uint_as_float(u & 0xffff0000u); }

// ---------------- k5: pack D=6 f32 rows -> bf16[*][8] (one uint4/row) ----------------

__global__ __launch_bounds__(256) void pack6_kernel(
    const float* __restrict__ xs, const float* __restrict__ xb,
    u32* __restrict__ xps, u32* __restrict__ xpb)
{
    int i = blockIdx.x * 256 + threadIdx.x;
    const int totS = NS * 4, tot = (NS + NB) * 4;
    if (i >= tot) return;
    const float* src; u32* dst; int j;
    if (i < totS) { src = xs; dst = xps; j = i; }
    else          { src = xb; dst = xpb; j = i - totS; }
    int node = j >> 2, w = j & 3;
    int d0 = 2 * w, d1 = 2 * w + 1;
    float a = (d0 < 6) ? src[(size_t)node * 6 + d0] : 0.f;
    float b = (d1 < 6) ? src[(size_t)node * 6 + d1] : 0.f;
    dst[j] = bfpack(a, b);
}

// ---------------- FRel ----------------

struct FRel {
    const int* rs;
    const int* srcs;
    const void* xsrc;
    const float* W;
    const float* b;
    const float* Wroot;
};

// ================= D=32 path: R13-proven (16-edge rounds, unpack+fmaf) =============

template <int AGGR>
__device__ __forceinline__ void gath32bf(const u32* __restrict__ xsrc,
                                         const int* __restrict__ srcs,
                                         int s0, int deg, int li, int l8,
                                         float (&acc)[8])
{
    float init = (AGGR == 2) ? -INFINITY : 0.f;
    #pragma unroll
    for (int d = 0; d < 8; ++d) acc[d] = init;
    int grp = l8 >> 2, q = l8 & 3;
    int lim = s0 + deg - 1;
    int obase = li & ~7;
    for (int bs = 0; bs < deg; bs += 16) {
        int a0 = s0 + bs + 2 * l8;
        int ix0 = srcs[a0 < lim ? a0 : lim];
        int ix1 = srcs[a0 + 1 < lim ? a0 + 1 : lim];
        #pragma unroll
        for (int sub = 0; sub < 8; ++sub) {
            int sa = __shfl(ix0, obase + sub, 64);
            int sb = __shfl(ix1, obase + sub, 64);
            int s = grp ? sb : sa;
            int e = bs + 2 * sub + grp;
            if (e < deg) {
                uint4 v = *reinterpret_cast<const uint4*>(xsrc + (size_t)s * 16 + q * 4);
                float f0 = bflo(v.x), f1 = bfhi(v.x), f2 = bflo(v.y), f3 = bfhi(v.y);
                float f4 = bflo(v.z), f5 = bfhi(v.z), f6 = bflo(v.w), f7 = bfhi(v.w);
                if (AGGR == 2) {
                    acc[0] = fmaxf(acc[0], f0); acc[1] = fmaxf(acc[1], f1);
                    acc[2] = fmaxf(acc[2], f2); acc[3] = fmaxf(acc[3], f3);
                    acc[4] = fmaxf(acc[4], f4); acc[5] = fmaxf(acc[5], f5);
                    acc[6] = fmaxf(acc[6], f6); acc[7] = fmaxf(acc[7], f7);
                } else {
                    acc[0] += f0; acc[1] += f1; acc[2] += f2; acc[3] += f3;
                    acc[4] += f4; acc[5] += f5; acc[6] += f6; acc[7] += f7;
                }
            }
        }
    }
    #pragma unroll
    for (int d = 0; d < 8; ++d) {
        float o = __shfl_xor(acc[d], 4, 64);
        acc[d] = (AGGR == 2) ? fmaxf(acc[d], o) : (acc[d] + o);
    }
}

template <int AGGR>
__device__ __forceinline__ void do_g32(const FRel& R, int node, int nd,
                                       int li, int l8, int nl, u32* aggP)
{
    int nodec = min(node, nd - 1);
    int s0 = R.rs[nodec];
    int deg = R.rs[nodec + 1] - s0;
    if (node >= nd) deg = 0;
    float acc[8];
    gath32bf<AGGR>((const u32*)R.xsrc, R.srcs, s0, deg, li, l8, acc);
    if (AGGR == 1) {
        float inv = 1.f / (float)max(deg, 1);
        #pragma unroll
        for (int d = 0; d < 8; ++d) acc[d] *= inv;
    }
    if (AGGR == 2 && deg == 0) {
        #pragma unroll
        for (int d = 0; d < 8; ++d) acc[d] = 0.f;
    }
    int grp = l8 >> 2, q = l8 & 3;
    uint2 o;
    if (grp == 0) { o.x = bfpack(acc[0], acc[1]); o.y = bfpack(acc[2], acc[3]); }
    else          { o.x = bfpack(acc[4], acc[5]); o.y = bfpack(acc[6], acc[7]); }
    *reinterpret_cast<uint2*>(aggP + nl * 16 + q * 4 + grp * 2) = o;
}

template <int NREL, bool RES, bool RELU, bool OUTBF, int A0, int A1, int A2>
__global__ __launch_bounds__(256, 8) void fused32_kernel(
    FRel r0, FRel r1, FRel r2,
    const void* xdst, void* outp, int nd)
{
    __shared__ u32 sWb[NREL * 16 * 32];
    __shared__ float sWr[32 * 32];
    __shared__ u32 aggP[NREL * 32 * 16];
    __shared__ u32 xP[32 * 16];

    int tid = threadIdx.x, li = tid & 63, l8 = tid & 7, nl = tid >> 3;
    int node = blockIdx.x * 32 + nl;
    bool valid = node < nd;

    for (int i = tid; i < 16 * 32; i += 256) {
        int k2 = i >> 5, dim = i & 31;
        sWb[0 * 512 + i] = bfpack(r0.W[(2 * k2) * 32 + dim], r0.W[(2 * k2 + 1) * 32 + dim]);
        if (NREL > 1) sWb[1 * 512 + i] = bfpack(r1.W[(2 * k2) * 32 + dim], r1.W[(2 * k2 + 1) * 32 + dim]);
        if (NREL > 2) sWb[2 * 512 + i] = bfpack(r2.W[(2 * k2) * 32 + dim], r2.W[(2 * k2 + 1) * 32 + dim]);
    }
    for (int i = tid; i < 32 * 32; i += 256) {
        float wv = r0.Wroot[i];
        if (NREL > 1) wv += r1.Wroot[i];
        if (NREL > 2) wv += r2.Wroot[i];
        sWr[i] = wv;
    }

    uint2 xv = {0u, 0u};
    if (valid) xv = *reinterpret_cast<const uint2*>((const u32*)xdst + (size_t)node * 16 + l8 * 2);
    xP[nl * 16 + l8 * 2] = xv.x;
    xP[nl * 16 + l8 * 2 + 1] = xv.y;

    do_g32<A0>(r0, node, nd, li, l8, nl, aggP + 0 * 512);
    if (NREL > 1) do_g32<A1>(r1, node, nd, li, l8, nl, aggP + 1 * 512);
    if (NREL > 2) do_g32<A2>(r2, node, nd, li, l8, nl, aggP + 2 * 512);

    __syncthreads();

    int dim = tid & 31, grp = tid >> 5;
    #pragma unroll
    for (int it = 0; it < 4; ++it) {
        int n2 = grp + it * 8;
        int gnode = blockIdx.x * 32 + n2;
        if (gnode < nd) {
            float mm = r0.b[dim];
            if (NREL > 1) mm += r1.b[dim];
            if (NREL > 2) mm += r2.b[dim];
            #pragma unroll
            for (int r = 0; r < NREL; ++r) {
                const u32* ar = aggP + r * 512 + n2 * 16;
                const u32* wr = sWb + r * 512;
                #pragma unroll
                for (int k2 = 0; k2 < 16; ++k2) {
                    u32 a = ar[k2];
                    u32 w = wr[k2 * 32 + dim];
                    mm = fmaf(bflo(a), bflo(w), mm);
                    mm = fmaf(bfhi(a), bfhi(w), mm);
                }
            }
            const u32* xr = xP + n2 * 16;
            #pragma unroll
            for (int k2 = 0; k2 < 16; ++k2) {
                u32 u = xr[k2];
                mm = fmaf(bflo(u), sWr[(2 * k2) * 32 + dim], mm);
                mm = fmaf(bfhi(u), sWr[(2 * k2 + 1) * 32 + dim], mm);
            }
            if (RES) {
                u32 u = xr[dim >> 1];
                mm += (dim & 1) ? bfhi(u) : bflo(u);
            }
            if (RELU) mm = fmaxf(mm, 0.f);
            if (OUTBF) ((u16*)outp)[(size_t)gnode * 32 + dim] = bf1(mm);
            else       ((float*)outp)[(size_t)gnode * 32 + dim] = mm;
        }
    }
}

// ================= D=6 layer-0 path (separate template; proven) =======

template <int AGGR>
__device__ __forceinline__ void gath6p(const u32* __restrict__ xsrc,
                                       const int* __restrict__ srcs,
                                       int s0, int deg, int l8, float (&acc)[6])
{
    float init = (AGGR == 2) ? -INFINITY : 0.f;
    #pragma unroll
    for (int d = 0; d < 6; ++d) acc[d] = init;
    for (int bs = 0; bs < deg; bs += 8) {
        int e = bs + l8;
        int a = s0 + (e < deg ? e : deg - 1);
        int idx = srcs[a];
        if (e < deg) {
            uint4 v = *reinterpret_cast<const uint4*>(xsrc + (size_t)idx * 4);
            float f0 = bflo(v.x), f1 = bfhi(v.x), f2 = bflo(v.y);
            float f3 = bfhi(v.y), f4 = bflo(v.z), f5 = bfhi(v.z);
            if (AGGR == 2) {
                acc[0] = fmaxf(acc[0], f0); acc[1] = fmaxf(acc[1], f1);
                acc[2] = fmaxf(acc[2], f2); acc[3] = fmaxf(acc[3], f3);
                acc[4] = fmaxf(acc[4], f4); acc[5] = fmaxf(acc[5], f5);
            } else {
                acc[0] += f0; acc[1] += f1; acc[2] += f2;
                acc[3] += f3; acc[4] += f4; acc[5] += f5;
            }
        }
    }
    #pragma unroll
    for (int m = 1; m <= 4; m <<= 1) {
        #pragma unroll
        for (int d = 0; d < 6; ++d) {
            float o = __shfl_xor(acc[d], m, 64);   // intra-octet, full-wave
            acc[d] = (AGGR == 2) ? fmaxf(acc[d], o) : (acc[d] + o);
        }
    }
}

template <int AGGR>
__device__ __forceinline__ void do_g6(const FRel& R, int node, int nd,
                                      int l8, int nl, float* aggF)
{
    int nodec = min(node, nd - 1);
    int s0 = R.rs[nodec];
    int deg = R.rs[nodec + 1] - s0;
    if (node >= nd) deg = 0;
    float acc[6];
    gath6p<AGGR>((const u32*)R.xsrc, R.srcs, s0, deg, l8, acc);
    if (AGGR == 1) {
        float inv = 1.f / (float)max(deg, 1);
        #pragma unroll
        for (int d = 0; d < 6; ++d) acc[d] *= inv;
    }
    if (AGGR == 2 && deg == 0) {
        #pragma unroll
        for (int d = 0; d < 6; ++d) acc[d] = 0.f;
    }
    if (l8 == 0) {
        #pragma unroll
        for (int d = 0; d < 6; ++d) aggF[nl * 8 + d] = acc[d];
        aggF[nl * 8 + 6] = 0.f; aggF[nl * 8 + 7] = 0.f;
    }
}

template <int NREL, int A0, int A1, int A2>
__global__ __launch_bounds__(256, 8) void fused6_kernel(
    FRel r0, FRel r1, FRel r2,
    const float* __restrict__ xdst, u16* __restrict__ outp, int nd)
{
    __shared__ float sW6[NREL * 6 * 32];
    __shared__ float sWr[6 * 32];
    __shared__ float aggF[NREL * 32 * 8];
    __shared__ float xF[32 * 8];

    int tid = threadIdx.x, l8 = tid & 7, nl = tid >> 3;
    int node = blockIdx.x * 32 + nl;
    bool valid = node < nd;

    for (int i = tid; i < 6 * 32; i += 256) {
        sW6[0 * 192 + i] = r0.W[i];
        if (NREL > 1) sW6[1 * 192 + i] = r1.W[i];
        if (NREL > 2) sW6[2 * 192 + i] = r2.W[i];
        float wv = r0.Wroot[i];
        if (NREL > 1) wv += r1.Wroot[i];
        if (NREL > 2) wv += r2.Wroot[i];
        sWr[i] = wv;
    }
    xF[nl * 8 + l8] = (valid && l8 < 6) ? xdst[(size_t)node * 6 + l8] : 0.f;

    do_g6<A0>(r0, node, nd, l8, nl, aggF + 0 * 256);
    if (NREL > 1) do_g6<A1>(r1, node, nd, l8, nl, aggF + 1 * 256);
    if (NREL > 2) do_g6<A2>(r2, node, nd, l8, nl, aggF + 2 * 256);

    __syncthreads();

    int dim = tid & 31, grp = tid >> 5;
    #pragma unroll
    for (int it = 0; it < 4; ++it) {
        int n2 = grp + it * 8;
        int gnode = blockIdx.x * 32 + n2;
        if (gnode < nd) {
            float mm = r0.b[dim];
            if (NREL > 1) mm += r1.b[dim];
            if (NREL > 2) mm += r2.b[dim];
            #pragma unroll
            for (int r = 0; r < NREL; ++r)
                #pragma unroll
                for (int k = 0; k < 6; ++k)
                    mm = fmaf(aggF[r * 256 + n2 * 8 + k], sW6[r * 192 + k * 32 + dim], mm);
            #pragma unroll
            for (int k = 0; k < 6; ++k)
                mm = fmaf(xF[n2 * 8 + k], sWr[k * 32 + dim], mm);
            outp[(size_t)gnode * 32 + dim] = bf1(mm);
        }
    }
}

// ---------------- host ----------------

static inline char* alignp(char* p, size_t a) {
    return (char*)(((uintptr_t)p + a - 1) & ~(a - 1));
}

extern "C" void kernel_launch(void* const* d_in, const int* in_sizes, int n_in,
                              void* d_out, int out_size, void* d_ws, size_t ws_size,
                              hipStream_t stream)
{
    const float* x_stroke = (const float*)d_in[0];
    const float* x_brep   = (const float*)d_in[1];
    const int* ei0 = (const int*)d_in[2];
    const int* ei1 = (const int*)d_in[3];
    const int* ei2 = (const int*)d_in[4];
    const int* ei3 = (const int*)d_in[5];
    const int* ei4 = (const int*)d_in[6];
    const float* W0_rel  = (const float*)d_in[7];
    const float* b0_rel  = (const float*)d_in[8];
    const float* W0_root = (const float*)d_in[9];
    const float* Wb_rel  = (const float*)d_in[10];
    const float* bb_rel  = (const float*)d_in[11];
    const float* Wb_root = (const float*)d_in[12];
    float* out = (float*)d_out;

    // ---- workspace ----
    char* A = alignp((char*)d_ws, 256);
    int* ebkt = (int*)A;                                 // 5*EE ints (dead after csr_kernel)
    u32* xs0 = (u32*)A;                                  // overlay after build
    u32* xb0 = xs0 + (size_t)NS * 16;
    u32* xps = xb0 + (size_t)NB * 16;                    // packed D=6 rows (overlay)
    u32* xpb = xps + (size_t)NS * 4;
    char* Aend = (char*)(ebkt + (size_t)5 * EE);
    u32* xs1 = (u32*)alignp(Aend, 256);
    u32* xb1 = xs1 + (size_t)NS * 16;
    int* edges_csr = (int*)alignp((char*)(xb1 + (size_t)NB * 16), 256);   // 5*EE
    int* rs_all = (int*)alignp((char*)(edges_csr + (size_t)5 * EE), 256); // 5*(NS+1)
    int* bcnt  = (int*)alignp((char*)(rs_all + 5 * (NS + 1)), 256);
    int* bbase = (int*)alignp((char*)(bcnt + 5 * NBK_S), 256);
    int* gcur  = (int*)alignp((char*)(bbase + 5 * NBK_S), 256);

    // ---- build ----
    hipMemsetAsync(bcnt, 0, 5 * NBK_S * sizeof(int), stream);
    hist_kernel<<<dim3(NCH, 5), 256, 0, stream>>>(ei0, ei1, ei2, ei3, ei4, bcnt);
    bscan_kernel<<<5, 512, 0, stream>>>(bcnt, bbase, gcur);
    sort_kernel<<<dim3(NSC, 5), 256, 0, stream>>>(ei0, ei1, ei2, ei3, ei4, ebkt, gcur);
    csr_kernel<<<dim3(NBK_S, 5), 256, 0, stream>>>(ebkt, bcnt, bbase, edges_csr, rs_all);
    pack6_kernel<<<((NS + NB) * 4 + 255) / 256, 256, 0, stream>>>(x_stroke, x_brep, xps, xpb);

    // ---- weights ----
    auto relW = [&](int l, int r) -> const float* {
        return l == 0 ? W0_rel + r * 6 * 32 : Wb_rel + ((l - 1) * 5 + r) * 32 * 32;
    };
    auto relB = [&](int l, int r) -> const float* {
        return l == 0 ? b0_rel + r * 32 : bb_rel + ((l - 1) * 5 + r) * 32;
    };
    auto relWr = [&](int l, int r) -> const float* {
        return l == 0 ? W0_root + r * 6 * 32 : Wb_root + ((l - 1) * 5 + r) * 32 * 32;
    };
    auto FR = [&](int l, int r, const void* xsrc) -> FRel {
        FRel R;
        R.rs = rs_all + r * (NS + 1);
        R.srcs = edges_csr + (size_t)r * EE;
        R.xsrc = xsrc;
        R.W = relW(l, r); R.b = relB(l, r); R.Wroot = relWr(l, r);
        return R;
    };

    const int GS = (NS + 31) / 32;   // 3125
    const int GB = (NB + 31) / 32;   // 1563

    // layer 0 (D=6, packed bf16 sources; f32 root; no residual) -> bf16 xs0/xb0
    fused6_kernel<3, 1, 0, 2><<<GS, 256, 0, stream>>>(
        FR(0, 0, xps), FR(0, 1, xps), FR(0, 4, xps), x_stroke, (u16*)xs0, NS);
    fused6_kernel<2, 1, 2, 0><<<GB, 256, 0, stream>>>(
        FR(0, 2, xps), FR(0, 3, xpb), FR(0, 2, xps), x_brep, (u16*)xb0, NB);

    // layers 1..3 (D=32 bf16, residual, ping-pong); layer 4 relu -> f32 d_out
    const u32* cs = xs0; const u32* cb = xb0;
    for (int l = 1; l <= 3; ++l) {
        u32* os = (l & 1) ? xs1 : xs0;
        u32* ob = (l & 1) ? xb1 : xb0;
        fused32_kernel<3, true, false, true, 1, 0, 2><<<GS, 256, 0, stream>>>(
            FR(l, 0, cs), FR(l, 1, cs), FR(l, 4, cs), cs, os, NS);
        fused32_kernel<2, true, false, true, 1, 2, 0><<<GB, 256, 0, stream>>>(
            FR(l, 2, cs), FR(l, 3, cb), FR(l, 2, cs), cb, ob, NB);
        cs = os; cb = ob;
    }
    fused32_kernel<3, true, true, false, 1, 0, 2><<<GS, 256, 0, stream>>>(
        FR(4, 0, cs), FR(4, 1, cs), FR(4, 4, cs), cs, out, NS);
    fused32_kernel<2, true, true, false, 1, 2, 0><<<GB, 256, 0, stream>>>(
        FR(4, 2, cs), FR(4, 3, cb), FR(4, 2, cs), cb, out + (size_t)NS * 32, NB);

    (void)in_sizes; (void)n_in; (void)out_size; (void)ws_size;
}

// Round 19
// 681.172 us; speedup vs baseline: 2.5250x; 1.0054x over previous
//
#include <hip/hip_runtime.h>
#include <math.h>

#define NS 100000
#define NB 50000
#define EE 1600000

#define BSH 8
#define BSZ 256                         // dst nodes per bucket
#define NBK_S ((NS + BSZ - 1) / BSZ)    // 391
#define NBK_B ((NB + BSZ - 1) / BSZ)    // 196
#define CHUNK 16384                     // hist chunking
#define NCH ((EE + CHUNK - 1) / CHUNK)  // 98
#define SCH 8192                        // sort chunking
#define NSC ((EE + SCH - 1) / SCH)      // 196

#define SRC_MASK 0x1FFFF
#define SSH 17

typedef unsigned int u32;
typedef unsigned short u16;

// ---------------- k1: per-chunk bucket histogram ----------------

__global__ __launch_bounds__(256) void hist_kernel(
    const int* __restrict__ e0, const int* __restrict__ e1, const int* __restrict__ e2,
    const int* __restrict__ e3, const int* __restrict__ e4, int* __restrict__ bcnt)
{
    int j = blockIdx.x, rel = blockIdx.y, tid = threadIdx.x;
    const int* ei = (rel == 0) ? e0 : (rel == 1) ? e1 : (rel == 2) ? e2 : (rel == 3) ? e3 : e4;
    int nb = (rel == 2 || rel == 3) ? NBK_B : NBK_S;
    __shared__ int hist[NBK_S];
    for (int i = tid; i < nb; i += 256) hist[i] = 0;
    __syncthreads();
    int es = j * CHUNK, ee2 = min(EE, es + CHUNK);
    for (int e = es + tid; e < ee2; e += 256)
        atomicAdd(&hist[ei[EE + e] >> BSH], 1);
    __syncthreads();
    for (int i = tid; i < nb; i += 256)
        if (hist[i]) atomicAdd(&bcnt[rel * NBK_S + i], hist[i]);
}

// ---------------- k2: per-relation bucket-base scan (+ cursor init) ----------------

__global__ __launch_bounds__(512) void bscan_kernel(const int* __restrict__ bcnt,
                                                    int* __restrict__ bbase,
                                                    int* __restrict__ gcur)
{
    int rel = blockIdx.x;
    int nb = (rel == 2 || rel == 3) ? NBK_B : NBK_S;
    __shared__ int s[512];
    int tid = threadIdx.x;
    int v = (tid < nb) ? bcnt[rel * NBK_S + tid] : 0;
    s[tid] = v;
    __syncthreads();
    for (int off = 1; off < 512; off <<= 1) {
        int t = (tid >= off) ? s[tid - off] : 0;
        __syncthreads();
        s[tid] += t;
        __syncthreads();
    }
    int ex = s[tid] - v;
    if (tid < nb) { bbase[rel * NBK_S + tid] = ex; gcur[rel * NBK_S + tid] = ex; }
}

// ---------------- k3: per-chunk LDS counting sort -> bucket-partitioned runs -------

__global__ __launch_bounds__(256, 4) void sort_kernel(
    const int* __restrict__ e0, const int* __restrict__ e1, const int* __restrict__ e2,
    const int* __restrict__ e3, const int* __restrict__ e4,
    int* __restrict__ ebkt, int* __restrict__ gcur)
{
    int j = blockIdx.x, rel = blockIdx.y, tid = threadIdx.x;
    const int* ei = (rel == 0) ? e0 : (rel == 1) ? e1 : (rel == 2) ? e2 : (rel == 3) ? e3 : e4;
    int nb = (rel == 2 || rel == 3) ? NBK_B : NBK_S;

    __shared__ int start[NBK_S + 1];
    __shared__ int cur[NBK_S];
    __shared__ int gbase[NBK_S];
    __shared__ int part[256];
    __shared__ int buf[SCH];

    int es = j * SCH, ee2 = min(EE, es + SCH);
    int n = ee2 - es;

    for (int i = tid; i < nb; i += 256) cur[i] = 0;     // cur = hist (temp)
    __syncthreads();
    for (int e = es + tid; e < ee2; e += 256)
        atomicAdd(&cur[ei[EE + e] >> BSH], 1);
    __syncthreads();

    int v0 = (2 * tid < nb) ? cur[2 * tid] : 0;
    int v1 = (2 * tid + 1 < nb) ? cur[2 * tid + 1] : 0;
    part[tid] = v0 + v1;
    __syncthreads();
    for (int off = 1; off < 256; off <<= 1) {
        int t = (tid >= off) ? part[tid - off] : 0;
        __syncthreads();
        part[tid] += t;
        __syncthreads();
    }
    int run = (tid > 0) ? part[tid - 1] : 0;
    if (2 * tid < nb) start[2 * tid] = run;
    if (2 * tid + 1 < nb) start[2 * tid + 1] = run + v0;
    if (tid == 0) start[nb] = n;
    __syncthreads();
    for (int i = tid; i < nb; i += 256) cur[i] = start[i];  // cursors
    __syncthreads();

    for (int e = es + tid; e < ee2; e += 256) {
        int s = ei[e], d = ei[EE + e];
        int pos = atomicAdd(&cur[d >> BSH], 1);
        buf[pos] = ((d & (BSZ - 1)) << SSH) | s;
    }
    for (int b = tid; b < nb; b += 256) {
        int c = start[b + 1] - start[b];
        gbase[b] = c ? atomicAdd(&gcur[rel * NBK_S + b], c) : 0;
    }
    __syncthreads();

    // stream out: 16-lane groups copy bucket runs (avg run ~21)
    int* eo = ebkt + (size_t)rel * EE;
    int w16 = tid >> 4, l16 = tid & 15;
    for (int b = w16; b < nb; b += 16) {
        int sb = start[b], c = start[b + 1] - sb, gb = gbase[b];
        for (int i = l16; i < c; i += 16)
            eo[gb + i] = buf[sb + i];
    }
}

// ---------------- k4: per-bucket CSR finalize ----------------

__global__ __launch_bounds__(256, 8) void csr_kernel(
    const int* __restrict__ ebkt, const int* __restrict__ bcnt, const int* __restrict__ bbase,
    int* __restrict__ edges_csr, int* __restrict__ rs_all)
{
    int bkt = blockIdx.x, rel = blockIdx.y, tid = threadIdx.x;
    int nb = (rel == 2 || rel == 3) ? NBK_B : NBK_S;
    if (bkt >= nb) return;
    int nd = (rel == 2 || rel == 3) ? NB : NS;

    int base = bbase[rel * NBK_S + bkt];
    int cnt = bcnt[rel * NBK_S + bkt];
    const int* span = ebkt + (size_t)rel * EE + base;
    int* rs = rs_all + rel * (NS + 1);

    __shared__ int h[BSZ], s[BSZ], cu[BSZ];
    h[tid] = 0;
    __syncthreads();
    for (int i = tid; i < cnt; i += 256)
        atomicAdd(&h[span[i] >> SSH], 1);
    __syncthreads();
    s[tid] = h[tid];
    __syncthreads();
    for (int off = 1; off < 256; off <<= 1) {
        int t = (tid >= off) ? s[tid - off] : 0;
        __syncthreads();
        s[tid] += t;
        __syncthreads();
    }
    int exv = s[tid] - h[tid];
    cu[tid] = exv;
    int node = bkt * BSZ + tid;
    if (node < nd) rs[node] = base + exv;
    if (bkt == nb - 1 && tid == 0) rs[nd] = base + cnt;
    __syncthreads();

    int* outp = edges_csr + (size_t)rel * EE;
    for (int i = tid; i < cnt; i += 256) {
        int p = span[i];
        int pos = atomicAdd(&cu[p >> SSH], 1);
        outp[base + pos] = p & SRC_MASK;
    }
}

// ---------------- bf16 helpers ----------------

__device__ __forceinline__ u32 bfpack(float a, float b) {
    u32 ua = __float_as_uint(a), ub = __float_as_uint(b);
    ua = (ua + 0x7fffu + ((ua >> 16) & 1u)) >> 16;
    ub = (ub + 0x7fffu + ((ub >> 16) & 1u)) >> 16;
    return ua | (ub << 16);
}
__device__ __forceinline__ u16 bf1(float f) {
    u32 u = __float_as_uint(f);
    return (u16)((u + 0x7fffu + ((u >> 16) & 1u)) >> 16);
}
__device__ __forceinline__ float bflo(u32 u) { return __uint_as_float(u << 16); }
__device__ __forceinline__ float bfhi(u32 u) { return __uint_as_float(u & 0xffff0000u); }

// ---------------- k5: pack D=6 f32 rows -> bf16[*][8] (one uint4/row) ----------------

__global__ __launch_bounds__(256) void pack6_kernel(
    const float* __restrict__ xs, const float* __restrict__ xb,
    u32* __restrict__ xps, u32* __restrict__ xpb)
{
    int i = blockIdx.x * 256 + threadIdx.x;
    const int totS = NS * 4, tot = (NS + NB) * 4;
    if (i >= tot) return;
    const float* src; u32* dst; int j;
    if (i < totS) { src = xs; dst = xps; j = i; }
    else          { src = xb; dst = xpb; j = i - totS; }
    int node = j >> 2, w = j & 3;
    int d0 = 2 * w, d1 = 2 * w + 1;
    float a = (d0 < 6) ? src[(size_t)node * 6 + d0] : 0.f;
    float b = (d1 < 6) ? src[(size_t)node * 6 + d1] : 0.f;
    dst[j] = bfpack(a, b);
}

// ---------------- FRel ----------------

struct FRel {
    const int* rs;
    const int* srcs;
    const void* xsrc;
    const float* W;
    const float* b;
    const float* Wroot;
};

// ================= D=32 path: R13-proven (16-edge rounds, unpack+fmaf) =============

template <int AGGR>
__device__ __forceinline__ void gath32bf(const u32* __restrict__ xsrc,
                                         const int* __restrict__ srcs,
                                         int s0, int deg, int li, int l8,
                                         float (&acc)[8])
{
    float init = (AGGR == 2) ? -INFINITY : 0.f;
    #pragma unroll
    for (int d = 0; d < 8; ++d) acc[d] = init;
    int grp = l8 >> 2, q = l8 & 3;
    int lim = s0 + deg - 1;
    int obase = li & ~7;
    for (int bs = 0; bs < deg; bs += 16) {
        int a0 = s0 + bs + 2 * l8;
        int ix0 = srcs[a0 < lim ? a0 : lim];
        int ix1 = srcs[a0 + 1 < lim ? a0 + 1 : lim];
        #pragma unroll
        for (int sub = 0; sub < 8; ++sub) {
            int sa = __shfl(ix0, obase + sub, 64);
            int sb = __shfl(ix1, obase + sub, 64);
            int s = grp ? sb : sa;
            int e = bs + 2 * sub + grp;
            if (e < deg) {
                uint4 v = *reinterpret_cast<const uint4*>(xsrc + (size_t)s * 16 + q * 4);
                float f0 = bflo(v.x), f1 = bfhi(v.x), f2 = bflo(v.y), f3 = bfhi(v.y);
                float f4 = bflo(v.z), f5 = bfhi(v.z), f6 = bflo(v.w), f7 = bfhi(v.w);
                if (AGGR == 2) {
                    acc[0] = fmaxf(acc[0], f0); acc[1] = fmaxf(acc[1], f1);
                    acc[2] = fmaxf(acc[2], f2); acc[3] = fmaxf(acc[3], f3);
                    acc[4] = fmaxf(acc[4], f4); acc[5] = fmaxf(acc[5], f5);
                    acc[6] = fmaxf(acc[6], f6); acc[7] = fmaxf(acc[7], f7);
                } else {
                    acc[0] += f0; acc[1] += f1; acc[2] += f2; acc[3] += f3;
                    acc[4] += f4; acc[5] += f5; acc[6] += f6; acc[7] += f7;
                }
            }
        }
    }
    #pragma unroll
    for (int d = 0; d < 8; ++d) {
        float o = __shfl_xor(acc[d], 4, 64);
        acc[d] = (AGGR == 2) ? fmaxf(acc[d], o) : (acc[d] + o);
    }
}

template <int AGGR>
__device__ __forceinline__ void do_g32(const FRel& R, int node, int nd,
                                       int li, int l8, int nl, u32* aggP)
{
    int nodec = min(node, nd - 1);
    int s0 = R.rs[nodec];
    int deg = R.rs[nodec + 1] - s0;
    if (node >= nd) deg = 0;
    float acc[8];
    gath32bf<AGGR>((const u32*)R.xsrc, R.srcs, s0, deg, li, l8, acc);
    if (AGGR == 1) {
        float inv = 1.f / (float)max(deg, 1);
        #pragma unroll
        for (int d = 0; d < 8; ++d) acc[d] *= inv;
    }
    if (AGGR == 2 && deg == 0) {
        #pragma unroll
        for (int d = 0; d < 8; ++d) acc[d] = 0.f;
    }
    int grp = l8 >> 2, q = l8 & 3;
    uint2 o;
    if (grp == 0) { o.x = bfpack(acc[0], acc[1]); o.y = bfpack(acc[2], acc[3]); }
    else          { o.x = bfpack(acc[4], acc[5]); o.y = bfpack(acc[6], acc[7]); }
    *reinterpret_cast<uint2*>(aggP + nl * 16 + q * 4 + grp * 2) = o;
}

template <int NREL, bool RES, bool RELU, bool OUTBF, int A0, int A1, int A2>
__global__ __launch_bounds__(256, 8) void fused32_kernel(
    FRel r0, FRel r1, FRel r2,
    const void* xdst, void* outp, int nd)
{
    __shared__ u32 sWb[NREL * 16 * 32];
    __shared__ float sWr[32 * 32];
    __shared__ u32 aggP[NREL * 32 * 16];
    __shared__ u32 xP[32 * 16];

    int tid = threadIdx.x, li = tid & 63, l8 = tid & 7, nl = tid >> 3;
    int node = blockIdx.x * 32 + nl;
    bool valid = node < nd;

    for (int i = tid; i < 16 * 32; i += 256) {
        int k2 = i >> 5, dim = i & 31;
        sWb[0 * 512 + i] = bfpack(r0.W[(2 * k2) * 32 + dim], r0.W[(2 * k2 + 1) * 32 + dim]);
        if (NREL > 1) sWb[1 * 512 + i] = bfpack(r1.W[(2 * k2) * 32 + dim], r1.W[(2 * k2 + 1) * 32 + dim]);
        if (NREL > 2) sWb[2 * 512 + i] = bfpack(r2.W[(2 * k2) * 32 + dim], r2.W[(2 * k2 + 1) * 32 + dim]);
    }
    for (int i = tid; i < 32 * 32; i += 256) {
        float wv = r0.Wroot[i];
        if (NREL > 1) wv += r1.Wroot[i];
        if (NREL > 2) wv += r2.Wroot[i];
        sWr[i] = wv;
    }

    uint2 xv = {0u, 0u};
    if (valid) xv = *reinterpret_cast<const uint2*>((const u32*)xdst + (size_t)node * 16 + l8 * 2);
    xP[nl * 16 + l8 * 2] = xv.x;
    xP[nl * 16 + l8 * 2 + 1] = xv.y;

    do_g32<A0>(r0, node, nd, li, l8, nl, aggP + 0 * 512);
    if (NREL > 1) do_g32<A1>(r1, node, nd, li, l8, nl, aggP + 1 * 512);
    if (NREL > 2) do_g32<A2>(r2, node, nd, li, l8, nl, aggP + 2 * 512);

    __syncthreads();

    int dim = tid & 31, grp = tid >> 5;
    #pragma unroll
    for (int it = 0; it < 4; ++it) {
        int n2 = grp + it * 8;
        int gnode = blockIdx.x * 32 + n2;
        if (gnode < nd) {
            float mm = r0.b[dim];
            if (NREL > 1) mm += r1.b[dim];
            if (NREL > 2) mm += r2.b[dim];
            #pragma unroll
            for (int r = 0; r < NREL; ++r) {
                const u32* ar = aggP + r * 512 + n2 * 16;
                const u32* wr = sWb + r * 512;
                #pragma unroll
                for (int k2 = 0; k2 < 16; ++k2) {
                    u32 a = ar[k2];
                    u32 w = wr[k2 * 32 + dim];
                    mm = fmaf(bflo(a), bflo(w), mm);
                    mm = fmaf(bfhi(a), bfhi(w), mm);
                }
            }
            const u32* xr = xP + n2 * 16;
            #pragma unroll
            for (int k2 = 0; k2 < 16; ++k2) {
                u32 u = xr[k2];
                mm = fmaf(bflo(u), sWr[(2 * k2) * 32 + dim], mm);
                mm = fmaf(bfhi(u), sWr[(2 * k2 + 1) * 32 + dim], mm);
            }
            if (RES) {
                u32 u = xr[dim >> 1];
                mm += (dim & 1) ? bfhi(u) : bflo(u);
            }
            if (RELU) mm = fmaxf(mm, 0.f);
            if (OUTBF) ((u16*)outp)[(size_t)gnode * 32 + dim] = bf1(mm);
            else       ((float*)outp)[(size_t)gnode * 32 + dim] = mm;
        }
    }
}

// ================= D=6 layer-0 path (separate template; proven) =======

template <int AGGR>
__device__ __forceinline__ void gath6p(const u32* __restrict__ xsrc,
                                       const int* __restrict__ srcs,
                                       int s0, int deg, int l8, float (&acc)[6])
{
    float init = (AGGR == 2) ? -INFINITY : 0.f;
    #pragma unroll
    for (int d = 0; d < 6; ++d) acc[d] = init;
    for (int bs = 0; bs < deg; bs += 8) {
        int e = bs + l8;
        int a = s0 + (e < deg ? e : deg - 1);
        int idx = srcs[a];
        if (e < deg) {
            uint4 v = *reinterpret_cast<const uint4*>(xsrc + (size_t)idx * 4);
            float f0 = bflo(v.x), f1 = bfhi(v.x), f2 = bflo(v.y);
            float f3 = bfhi(v.y), f4 = bflo(v.z), f5 = bfhi(v.z);
            if (AGGR == 2) {
                acc[0] = fmaxf(acc[0], f0); acc[1] = fmaxf(acc[1], f1);
                acc[2] = fmaxf(acc[2], f2); acc[3] = fmaxf(acc[3], f3);
                acc[4] = fmaxf(acc[4], f4); acc[5] = fmaxf(acc[5], f5);
            } else {
                acc[0] += f0; acc[1] += f1; acc[2] += f2;
                acc[3] += f3; acc[4] += f4; acc[5] += f5;
            }
        }
    }
    #pragma unroll
    for (int m = 1; m <= 4; m <<= 1) {
        #pragma unroll
        for (int d = 0; d < 6; ++d) {
            float o = __shfl_xor(acc[d], m, 64);   // intra-octet, full-wave
            acc[d] = (AGGR == 2) ? fmaxf(acc[d], o) : (acc[d] + o);
        }
    }
}

template <int AGGR>
__device__ __forceinline__ void do_g6(const FRel& R, int node, int nd,
                                      int l8, int nl, float* aggF)
{
    int nodec = min(node, nd - 1);
    int s0 = R.rs[nodec];
    int deg = R.rs[nodec + 1] - s0;
    if (node >= nd) deg = 0;
    float acc[6];
    gath6p<AGGR>((const u32*)R.xsrc, R.srcs, s0, deg, l8, acc);
    if (AGGR == 1) {
        float inv = 1.f / (float)max(deg, 1);
        #pragma unroll
        for (int d = 0; d < 6; ++d) acc[d] *= inv;
    }
    if (AGGR == 2 && deg == 0) {
        #pragma unroll
        for (int d = 0; d < 6; ++d) acc[d] = 0.f;
    }
    if (l8 == 0) {
        #pragma unroll
        for (int d = 0; d < 6; ++d) aggF[nl * 8 + d] = acc[d];
        aggF[nl * 8 + 6] = 0.f; aggF[nl * 8 + 7] = 0.f;
    }
}

template <int NREL, int A0, int A1, int A2>
__global__ __launch_bounds__(256, 8) void fused6_kernel(
    FRel r0, FRel r1, FRel r2,
    const float* __restrict__ xdst, u16* __restrict__ outp, int nd)
{
    __shared__ float sW6[NREL * 6 * 32];
    __shared__ float sWr[6 * 32];
    __shared__ float aggF[NREL * 32 * 8];
    __shared__ float xF[32 * 8];

    int tid = threadIdx.x, l8 = tid & 7, nl = tid >> 3;
    int node = blockIdx.x * 32 + nl;
    bool valid = node < nd;

    for (int i = tid; i < 6 * 32; i += 256) {
        sW6[0 * 192 + i] = r0.W[i];
        if (NREL > 1) sW6[1 * 192 + i] = r1.W[i];
        if (NREL > 2) sW6[2 * 192 + i] = r2.W[i];
        float wv = r0.Wroot[i];
        if (NREL > 1) wv += r1.Wroot[i];
        if (NREL > 2) wv += r2.Wroot[i];
        sWr[i] = wv;
    }
    xF[nl * 8 + l8] = (valid && l8 < 6) ? xdst[(size_t)node * 6 + l8] : 0.f;

    do_g6<A0>(r0, node, nd, l8, nl, aggF + 0 * 256);
    if (NREL > 1) do_g6<A1>(r1, node, nd, l8, nl, aggF + 1 * 256);
    if (NREL > 2) do_g6<A2>(r2, node, nd, l8, nl, aggF + 2 * 256);

    __syncthreads();

    int dim = tid & 31, grp = tid >> 5;
    #pragma unroll
    for (int it = 0; it < 4; ++it) {
        int n2 = grp + it * 8;
        int gnode = blockIdx.x * 32 + n2;
        if (gnode < nd) {
            float mm = r0.b[dim];
            if (NREL > 1) mm += r1.b[dim];
            if (NREL > 2) mm += r2.b[dim];
            #pragma unroll
            for (int r = 0; r < NREL; ++r)
                #pragma unroll
                for (int k = 0; k < 6; ++k)
                    mm = fmaf(aggF[r * 256 + n2 * 8 + k], sW6[r * 192 + k * 32 + dim], mm);
            #pragma unroll
            for (int k = 0; k < 6; ++k)
                mm = fmaf(xF[n2 * 8 + k], sWr[k * 32 + dim], mm);
            outp[(size_t)gnode * 32 + dim] = bf1(mm);
        }
    }
}

// ---------------- host ----------------

static inline char* alignp(char* p, size_t a) {
    return (char*)(((uintptr_t)p + a - 1) & ~(a - 1));
}

extern "C" void kernel_launch(void* const* d_in, const int* in_sizes, int n_in,
                              void* d_out, int out_size, void* d_ws, size_t ws_size,
                              hipStream_t stream)
{
    const float* x_stroke = (const float*)d_in[0];
    const float* x_brep   = (const float*)d_in[1];
    const int* ei0 = (const int*)d_in[2];
    const int* ei1 = (const int*)d_in[3];
    const int* ei2 = (const int*)d_in[4];
    const int* ei3 = (const int*)d_in[5];
    const int* ei4 = (const int*)d_in[6];
    const float* W0_rel  = (const float*)d_in[7];
    const float* b0_rel  = (const float*)d_in[8];
    const float* W0_root = (const float*)d_in[9];
    const float* Wb_rel  = (const float*)d_in[10];
    const float* bb_rel  = (const float*)d_in[11];
    const float* Wb_root = (const float*)d_in[12];
    float* out = (float*)d_out;

    // ---- workspace ----
    char* A = alignp((char*)d_ws, 256);
    int* ebkt = (int*)A;                                 // 5*EE ints (dead after csr_kernel)
    u32* xs0 = (u32*)A;                                  // overlay after build
    u32* xb0 = xs0 + (size_t)NS * 16;
    u32* xps = xb0 + (size_t)NB * 16;                    // packed D=6 rows (overlay)
    u32* xpb = xps + (size_t)NS * 4;
    char* Aend = (char*)(ebkt + (size_t)5 * EE);
    u32* xs1 = (u32*)alignp(Aend, 256);
    u32* xb1 = xs1 + (size_t)NS * 16;
    int* edges_csr = (int*)alignp((char*)(xb1 + (size_t)NB * 16), 256);   // 5*EE
    int* rs_all = (int*)alignp((char*)(edges_csr + (size_t)5 * EE), 256); // 5*(NS+1)
    int* bcnt  = (int*)alignp((char*)(rs_all + 5 * (NS + 1)), 256);
    int* bbase = (int*)alignp((char*)(bcnt + 5 * NBK_S), 256);
    int* gcur  = (int*)alignp((char*)(bbase + 5 * NBK_S), 256);

    // ---- build ----
    hipMemsetAsync(bcnt, 0, 5 * NBK_S * sizeof(int), stream);
    hist_kernel<<<dim3(NCH, 5), 256, 0, stream>>>(ei0, ei1, ei2, ei3, ei4, bcnt);
    bscan_kernel<<<5, 512, 0, stream>>>(bcnt, bbase, gcur);
    sort_kernel<<<dim3(NSC, 5), 256, 0, stream>>>(ei0, ei1, ei2, ei3, ei4, ebkt, gcur);
    csr_kernel<<<dim3(NBK_S, 5), 256, 0, stream>>>(ebkt, bcnt, bbase, edges_csr, rs_all);
    pack6_kernel<<<((NS + NB) * 4 + 255) / 256, 256, 0, stream>>>(x_stroke, x_brep, xps, xpb);

    // ---- weights ----
    auto relW = [&](int l, int r) -> const float* {
        return l == 0 ? W0_rel + r * 6 * 32 : Wb_rel + ((l - 1) * 5 + r) * 32 * 32;
    };
    auto relB = [&](int l, int r) -> const float* {
        return l == 0 ? b0_rel + r * 32 : bb_rel + ((l - 1) * 5 + r) * 32;
    };
    auto relWr = [&](int l, int r) -> const float* {
        return l == 0 ? W0_root + r * 6 * 32 : Wb_root + ((l - 1) * 5 + r) * 32 * 32;
    };
    auto FR = [&](int l, int r, const void* xsrc) -> FRel {
        FRel R;
        R.rs = rs_all + r * (NS + 1);
        R.srcs = edges_csr + (size_t)r * EE;
        R.xsrc = xsrc;
        R.W = relW(l, r); R.b = relB(l, r); R.Wroot = relWr(l, r);
        return R;
    };

    const int GS = (NS + 31) / 32;   // 3125
    const int GB = (NB + 31) / 32;   // 1563

    // layer 0 (D=6, packed bf16 sources; f32 root; no residual) -> bf16 xs0/xb0
    fused6_kernel<3, 1, 0, 2><<<GS, 256, 0, stream>>>(
        FR(0, 0, xps), FR(0, 1, xps), FR(0, 4, xps), x_stroke, (u16*)xs0, NS);
    fused6_kernel<2, 1, 2, 0><<<GB, 256, 0, stream>>>(
        FR(0, 2, xps), FR(0, 3, xpb), FR(0, 2, xps), x_brep, (u16*)xb0, NB);

    // layers 1..3 (D=32 bf16, residual, ping-pong); layer 4 relu -> f32 d_out
    const u32* cs = xs0; const u32* cb = xb0;
    for (int l = 1; l <= 3; ++l) {
        u32* os = (l & 1) ? xs1 : xs0;
        u32* ob = (l & 1) ? xb1 : xb0;
        fused32_kernel<3, true, false, true, 1, 0, 2><<<GS, 256, 0, stream>>>(
            FR(l, 0, cs), FR(l, 1, cs), FR(l, 4, cs), cs, os, NS);
        fused32_kernel<2, true, false, true, 1, 2, 0><<<GB, 256, 0, stream>>>(
            FR(l, 2, cs), FR(l, 3, cb), FR(l, 2, cs), cb, ob, NB);
        cs = os; cb = ob;
    }
    fused32_kernel<3, true, true, false, 1, 0, 2><<<GS, 256, 0, stream>>>(
        FR(4, 0, cs), FR(4, 1, cs), FR(4, 4, cs), cs, out, NS);
    fused32_kernel<2, true, true, false, 1, 2, 0><<<GB, 256, 0, stream>>>(
        FR(4, 2, cs), FR(4, 3, cb), FR(4, 2, cs), cb, out + (size_t)NS * 32, NB);

    (void)in_sizes; (void)n_in; (void)out_size; (void)ws_size;
}